// Round 15
// baseline (101.449 us; speedup 1.0000x reference)
//
#include <hip/hip_runtime.h>
#include <hip/hip_bf16.h>
#include <math.h>

#define DD 128
#define MAXDEG 64
#define BKT 64               // dst rows per bucket (partition granularity)
#define SBKT 16              // rows per K4 block (4 blocks per bucket)
#define NB_MAX 1024
#define P_CH 8192            // edges per partition block
#define HBINS 16384          // bins per deg_src histogram pass (64KB LDS)
#define HBLK  32

using bf16x8 = __attribute__((ext_vector_type(8))) short;
using f32x4  = __attribute__((ext_vector_type(4))) float;

struct alignas(16) bfq { __hip_bfloat162 q[4]; };

__device__ inline float bf2f(short s) {
    unsigned int u = ((unsigned int)(unsigned short)s) << 16;
    float f;
    __builtin_memcpy(&f, &u, 4);
    return f;
}

// ====== K1: conv h->bf16 unscaled (A) + deg_src hist (B) + bucket count (C) + Wt (D)
__global__ __launch_bounds__(1024) void k1_kernel(
        const float* __restrict__ h, __hip_bfloat16* __restrict__ hb,
        const int* __restrict__ src, const int* __restrict__ dst,
        unsigned int* __restrict__ parts, unsigned int* __restrict__ bucket_cnt,
        const float* __restrict__ Wm, __hip_bfloat16* __restrict__ Wt,
        int E, int NB, int num_src, int nConv, int nHist, int nPc) {
    __shared__ unsigned int smem[HBINS];   // 64KB
    int t = threadIdx.x;
    int bid = blockIdx.x;
    if (bid < nConv) {
        int idx = bid * 1024 + t;          // one thread per 8 elems
        int total = num_src * (DD / 8);
        if (idx >= total) return;
        int row = idx >> 4;
        int c0  = (idx & 15) * 8;
        const float4* p = reinterpret_cast<const float4*>(h + (size_t)row * DD + c0);
        float4 a = p[0], b = p[1];
        bfq o;
        o.q[0] = __float22bfloat162_rn(make_float2(a.x, a.y));
        o.q[1] = __float22bfloat162_rn(make_float2(a.z, a.w));
        o.q[2] = __float22bfloat162_rn(make_float2(b.x, b.y));
        o.q[3] = __float22bfloat162_rn(make_float2(b.z, b.w));
        *reinterpret_cast<bfq*>(hb + (size_t)row * DD + c0) = o;
    } else if (bid < nConv + nHist) {
        int hbid = bid - nConv;
        int pass = hbid / HBLK;
        int blk  = hbid % HBLK;
        int lo   = pass * HBINS;
        for (int i = t; i < HBINS; i += 1024) smem[i] = 0;
        __syncthreads();
        int chunk = (E + HBLK - 1) / HBLK;
        int c0 = blk * chunk;
        int c1 = c0 + chunk; if (c1 > E) c1 = E;
        for (int i = c0 + t; i < c1; i += 1024) {
            unsigned int u = (unsigned int)(src[i] - lo);
            if (u < HBINS) atomicAdd(&smem[u], 1u);
        }
        __syncthreads();
        unsigned int* dstp = parts + ((size_t)hbid << 14);
        for (int i = t; i < HBINS; i += 1024) dstp[i] = smem[i];
    } else if (bid < nConv + nHist + nPc) {
        int b2 = bid - nConv - nHist;
        for (int b = t; b < NB; b += 1024) smem[b] = 0;
        __syncthreads();
        int c0 = b2 * P_CH;
        int c1 = c0 + P_CH; if (c1 > E) c1 = E;
        for (int i = c0 + t; i < c1; i += 1024)
            atomicAdd(&smem[dst[i] >> 6], 1u);
        __syncthreads();
        for (int b = t; b < NB; b += 1024)
            if (smem[b]) atomicAdd(&bucket_cnt[b], smem[b]);
    } else {
        int idx = (bid - nConv - nHist - nPc) * 1024 + t;
        if (idx < DD * DD) {
            int c = idx >> 7, k = idx & 127;
            Wt[idx] = __float2bfloat16(Wm[k * DD + c]);
        }
    }
}

// =============== K2: hist merge (role A) + bucket exclusive scan (role B)
__global__ __launch_bounds__(256) void k2_kernel(
        const unsigned int* __restrict__ parts, unsigned int* __restrict__ deg_src,
        int num_src, const unsigned int* __restrict__ bucket_cnt,
        unsigned int* __restrict__ bucket_base, unsigned int* __restrict__ bucket_cur,
        int NB, int nMerge) {
    int bid = blockIdx.x;
    if (bid < nMerge) {
        int g = bid * 256 + threadIdx.x;
        if (g >= num_src) return;
        int pass = g >> 14;
        int r = g & (HBINS - 1);
        const unsigned int* p = parts + ((size_t)(pass * HBLK) << 14) + r;
        unsigned int s = 0;
#pragma unroll
        for (int b = 0; b < HBLK; ++b) s += p[(size_t)b << 14];
        deg_src[g] = s;
    } else {
        int lane = threadIdx.x;
        if (lane >= 64) return;
        unsigned int carry = 0;
        for (int b0 = 0; b0 < NB; b0 += 64) {
            int i = b0 + lane;
            unsigned int v = (i < NB) ? bucket_cnt[i] : 0u;
            unsigned int incl = v;
#pragma unroll
            for (int off = 1; off < 64; off <<= 1) {
                unsigned int u = __shfl_up(incl, off);
                if (lane >= off) incl += u;
            }
            unsigned int excl = incl - v + carry;
            if (i < NB) { bucket_base[i] = excl; bucket_cur[i] = excl; }
            carry += __shfl(incl, 63);
        }
        if (lane == 0) bucket_base[NB] = carry;
    }
}

// =============== K3: hb in-place scale by rsqrt(deg_src) (A) + pscatter (B)
__global__ __launch_bounds__(1024) void k3_kernel(
        const unsigned int* __restrict__ deg_src, __hip_bfloat16* __restrict__ hb,
        const int* __restrict__ src, const int* __restrict__ dst,
        unsigned int* __restrict__ bucket_cur, unsigned int* __restrict__ eparts,
        int E, int NB, int num_src, int nScale) {
    __shared__ unsigned int smem[15360];   // 60KB (pscatter role)
    int t = threadIdx.x;
    int bid = blockIdx.x;
    if (bid < nScale) {
        int idx = bid * 1024 + t;          // one thread per 8 elems
        int total = num_src * (DD / 8);
        if (idx >= total) return;
        int row = idx >> 4;
        int c0  = (idx & 15) * 8;
        float nrm = rsqrtf(fmaxf((float)deg_src[row], 1.0f));
        bfq v = *reinterpret_cast<const bfq*>(hb + (size_t)row * DD + c0);
        bfq o;
#pragma unroll
        for (int j = 0; j < 4; ++j) {
            float2 f = __bfloat1622float2(v.q[j]);
            o.q[j] = __float22bfloat162_rn(make_float2(f.x * nrm, f.y * nrm));
        }
        *reinterpret_cast<bfq*>(hb + (size_t)row * DD + c0) = o;
    } else {
        int b2 = bid - nScale;
        unsigned int*   stage_s = smem;                             // 8192 u32
        unsigned short* stage_d = (unsigned short*)(smem + 8192);   // 8192 u16
        unsigned int*   lhist   = smem + 12288;                     // 1024
        unsigned int*   lbase   = smem + 13312;                     // 1024
        unsigned int*   gbase   = smem + 14336;                     // 1024
        for (int b = t; b < NB_MAX; b += 1024) lhist[b] = 0;
        __syncthreads();
        int c0 = b2 * P_CH;
        int cnt = E - c0; if (cnt > P_CH) cnt = P_CH;
        int dreg[8], sreg[8];
#pragma unroll
        for (int k = 0; k < 8; ++k) {
            int j = t + k * 1024;
            if (j < cnt) {
                dreg[k] = dst[c0 + j];
                sreg[k] = src[c0 + j];
                atomicAdd(&lhist[dreg[k] >> 6], 1u);
            }
        }
        __syncthreads();
        // wave-shuffle exclusive scan of lhist[0..1023] (2 barriers)
        int wid = t >> 6, lane = t & 63;
        unsigned int v = lhist[t];
        unsigned int x = v;
#pragma unroll
        for (int off = 1; off < 64; off <<= 1) {
            unsigned int u = __shfl_up(x, off);
            if (lane >= off) x += u;
        }
        if (lane == 63) gbase[wid] = x;    // wave sums (gbase[0..15] scratch)
        __syncthreads();
        if (t < 16) {
            unsigned int w = gbase[t];
            unsigned int y = w;
#pragma unroll
            for (int off = 1; off < 16; off <<= 1) {
                unsigned int u = __shfl_up(y, off);
                if (t >= off) y += u;
            }
            gbase[t] = y - w;              // exclusive wave offset
        }
        __syncthreads();
        unsigned int excl = x - v + gbase[wid];
        __syncthreads();                    // gbase reads done before overwrite
        lbase[t] = excl;
        if (t < NB) {
            unsigned int c = lhist[t];
            gbase[t] = c ? atomicAdd(&bucket_cur[t], c) : 0u;
            lhist[t] = 0u;                 // reuse as local cursor
        }
        __syncthreads();
#pragma unroll
        for (int k = 0; k < 8; ++k) {
            int j = t + k * 1024;
            if (j < cnt) {
                int bin = dreg[k] >> 6;
                unsigned int pos = lbase[bin] + atomicAdd(&lhist[bin], 1u);
                stage_d[pos] = (unsigned short)dreg[k];
                stage_s[pos] = (unsigned int)sreg[k];
            }
        }
        __syncthreads();
        for (int idx = t; idx < cnt; idx += 1024) {
            unsigned int d = stage_d[idx];
            unsigned int bin = d >> 6;
            unsigned int pos = gbase[bin] + ((unsigned int)idx - lbase[bin]);
            eparts[pos] = ((d & 63u) << 24) | stage_s[idx];
        }
    }
}

// =============== K4: sub-bucket gather + MFMA GEMM + epilogue (R12 verbatim)
__global__ __launch_bounds__(256) void bgather_mfma_kernel(
        const __hip_bfloat16* __restrict__ hb,
        const unsigned int* __restrict__ eparts,
        const unsigned int* __restrict__ bucket_base,
        const __hip_bfloat16* __restrict__ Wt,
        const float* __restrict__ bias, const float* __restrict__ w_attn,
        float* __restrict__ out, float* __restrict__ alpha_out, int num_dst) {
    __shared__ unsigned int lcsr[SBKT * MAXDEG];   // 4KB
    __shared__ unsigned int cur[SBKT];
    __shared__ __hip_bfloat16 sagg[SBKT * DD];     // 4KB, XOR-swizzled
    int t = threadIdx.x, wid = t >> 6, lane = t & 63;
    int b = blockIdx.x >> 2;
    unsigned int quarter = blockIdx.x & 3;
    if (t < SBKT) cur[t] = 0;
    __syncthreads();
    unsigned int e0 = bucket_base[b], e1 = bucket_base[b + 1];
    for (unsigned int i = e0 + t; i < e1; i += 256) {
        unsigned int e = eparts[i];
        unsigned int dlow = e >> 24;
        if ((dlow >> 4) == quarter) {
            unsigned int pos = atomicAdd(&cur[dlow & 15], 1u);   // LDS int atomic
            if (pos < MAXDEG) lcsr[(dlow & 15) * MAXDEG + pos] = e & 0xFFFFFFu;
        }
    }
    __syncthreads();

    const bf16x8* hb8 = reinterpret_cast<const bf16x8*>(hb);  // 16 chunks/row
    char* sb = (char*)sagg;
    int g  = lane >> 4;     // row-group 0..3
    int gl = lane & 15;     // 16B chunk within row
    {
        int r = wid * 4 + g;                 // 0..15
        unsigned int degu = cur[r];
        int deg = (int)degu; if (deg > MAXDEG) deg = MAXDEG;
        const unsigned int* crow = &lcsr[r * MAXDEG];
        float acc[8];
#pragma unroll
        for (int j = 0; j < 8; ++j) acc[j] = 0.f;
        int i = 0;
        for (; i + 8 <= deg; i += 8) {
            uint4 qa = *reinterpret_cast<const uint4*>(crow + i);      // broadcast
            uint4 qb = *reinterpret_cast<const uint4*>(crow + i + 4);
            bf16x8 v0 = hb8[(size_t)qa.x * 16 + gl];
            bf16x8 v1 = hb8[(size_t)qa.y * 16 + gl];
            bf16x8 v2 = hb8[(size_t)qa.z * 16 + gl];
            bf16x8 v3 = hb8[(size_t)qa.w * 16 + gl];
            bf16x8 v4 = hb8[(size_t)qb.x * 16 + gl];
            bf16x8 v5 = hb8[(size_t)qb.y * 16 + gl];
            bf16x8 v6 = hb8[(size_t)qb.z * 16 + gl];
            bf16x8 v7 = hb8[(size_t)qb.w * 16 + gl];
#pragma unroll
            for (int j = 0; j < 8; ++j)
                acc[j] += ((bf2f(v0[j]) + bf2f(v1[j])) + (bf2f(v2[j]) + bf2f(v3[j])))
                        + ((bf2f(v4[j]) + bf2f(v5[j])) + (bf2f(v6[j]) + bf2f(v7[j])));
        }
        for (; i + 4 <= deg; i += 4) {
            uint4 q = *reinterpret_cast<const uint4*>(crow + i);
            bf16x8 v0 = hb8[(size_t)q.x * 16 + gl];
            bf16x8 v1 = hb8[(size_t)q.y * 16 + gl];
            bf16x8 v2 = hb8[(size_t)q.z * 16 + gl];
            bf16x8 v3 = hb8[(size_t)q.w * 16 + gl];
#pragma unroll
            for (int j = 0; j < 8; ++j)
                acc[j] += (bf2f(v0[j]) + bf2f(v1[j])) + (bf2f(v2[j]) + bf2f(v3[j]));
        }
        for (; i < deg; ++i) {
            bf16x8 v = hb8[(size_t)crow[i] * 16 + gl];
#pragma unroll
            for (int j = 0; j < 8; ++j) acc[j] += bf2f(v[j]);
        }
        float scd = rsqrtf(fmaxf((float)degu, 1.0f));
        bfq o;
#pragma unroll
        for (int j = 0; j < 4; ++j)
            o.q[j] = __float22bfloat162_rn(
                make_float2(acc[2 * j] * scd, acc[2 * j + 1] * scd));
        int byte = r * 256 + gl * 16;
        *reinterpret_cast<bfq*>(sb + (byte ^ ((r & 7) << 4))) = o;
    }
    __syncthreads();

    if (wid == 0) {
        int col = lane & 15, hi = lane >> 4;
        int row0 = b * 64 + quarter * 16;
        f32x4 acc[8];
#pragma unroll
        for (int ct = 0; ct < 8; ++ct) acc[ct] = (f32x4)0.f;
#pragma unroll
        for (int kg = 0; kg < 4; ++kg) {
            int byte = col * 256 + (kg * 32 + hi * 8) * 2;
            bf16x8 a = *reinterpret_cast<const bf16x8*>(
                sb + (byte ^ ((col & 7) << 4)));
#pragma unroll
            for (int ct = 0; ct < 8; ++ct) {
                const bf16x8* B = reinterpret_cast<const bf16x8*>(
                    Wt + (size_t)(ct * 16 + col) * DD);
                bf16x8 bb = B[kg * 4 + hi];
                acc[ct] = __builtin_amdgcn_mfma_f32_16x16x32_bf16(a, bb, acc[ct],
                                                                  0, 0, 0);
            }
        }
        float wv[8], bv[8];
#pragma unroll
        for (int ct = 0; ct < 8; ++ct) {
            wv[ct] = w_attn[ct * 16 + col];
            bv[ct] = bias[ct * 16 + col];
        }
#pragma unroll
        for (int r = 0; r < 4; ++r) {
            int row = row0 + hi * 4 + r;
            float v[8];
            float s = 0.f;
#pragma unroll
            for (int ct = 0; ct < 8; ++ct) {
                v[ct] = acc[ct][r] + bv[ct];
                s = fmaf(v[ct], wv[ct], s);
            }
            s += __shfl_xor(s, 1);
            s += __shfl_xor(s, 2);
            s += __shfl_xor(s, 4);
            s += __shfl_xor(s, 8);
            float alpha = 1.0f / (1.0f + expf(-s));
            if (row < num_dst) {
#pragma unroll
                for (int ct = 0; ct < 8; ++ct)
                    out[(size_t)row * DD + ct * 16 + col] = v[ct] * alpha;
                if (col == 0) alpha_out[row] = alpha;
            }
        }
    }
}

// =============== fallback-path kernels (non-bucket shapes / small ws)
__global__ void hist_atomic_kernel(const int* __restrict__ src,
                                   unsigned int* __restrict__ deg_src, int E) {
    int i = blockIdx.x * blockDim.x + threadIdx.x;
    if (i < E) atomicAdd(&deg_src[src[i]], 1u);
}

__global__ void fillc_kernel(const int* __restrict__ src, const int* __restrict__ dst,
                             unsigned int* __restrict__ cursor,
                             int* __restrict__ csr, int E) {
    int i = blockIdx.x * blockDim.x + threadIdx.x;
    if (i < E) {
        int s = src[i];
        int d = dst[i];
        unsigned int pos = atomicAdd(&cursor[d], 1u);
        if (pos < MAXDEG) csr[(size_t)d * MAXDEG + pos] = s;
    }
}

__global__ __launch_bounds__(256) void gather_kernel(
        const __hip_bfloat16* __restrict__ hb,
        const int* __restrict__ csr, const unsigned int* __restrict__ cursor,
        __hip_bfloat16* __restrict__ aggb, int num_dst) {
    int wave = threadIdx.x >> 6;
    int lane = threadIdx.x & 63;
    int row = blockIdx.x * 4 + wave;
    if (row >= num_dst) return;
    unsigned int degu = cursor[row];
    int deg = (int)degu; if (deg > MAXDEG) deg = MAXDEG;
    const int* crow = csr + (size_t)row * MAXDEG;
    int c = lane * 2;
    float ax = 0.f, ay = 0.f;
    int i = 0;
    for (; i + 4 <= deg; i += 4) {
        int4 s0 = *reinterpret_cast<const int4*>(crow + i);
        float2 v0 = __bfloat1622float2(*reinterpret_cast<const __hip_bfloat162*>(hb + (size_t)s0.x * DD + c));
        float2 v1 = __bfloat1622float2(*reinterpret_cast<const __hip_bfloat162*>(hb + (size_t)s0.y * DD + c));
        float2 v2 = __bfloat1622float2(*reinterpret_cast<const __hip_bfloat162*>(hb + (size_t)s0.z * DD + c));
        float2 v3 = __bfloat1622float2(*reinterpret_cast<const __hip_bfloat162*>(hb + (size_t)s0.w * DD + c));
        ax += v0.x + v1.x + v2.x + v3.x;
        ay += v0.y + v1.y + v2.y + v3.y;
    }
    for (; i < deg; ++i) {
        int s = crow[i];
        float2 vv = __bfloat1622float2(*reinterpret_cast<const __hip_bfloat162*>(hb + (size_t)s * DD + c));
        ax += vv.x; ay += vv.y;
    }
    float scd = rsqrtf(fmaxf((float)degu, 1.0f));
    *reinterpret_cast<__hip_bfloat162*>(aggb + (size_t)row * DD + c) =
        __float22bfloat162_rn(make_float2(ax * scd, ay * scd));
}

__global__ __launch_bounds__(256) void out_mfma_kernel(
        const __hip_bfloat16* __restrict__ aggb,
        const __hip_bfloat16* __restrict__ Wt,
        const float* __restrict__ bias, const float* __restrict__ w_attn,
        float* __restrict__ out, float* __restrict__ alpha_out, int num_dst) {
    int wave = threadIdx.x >> 6;
    int lane = threadIdx.x & 63;
    int row0 = blockIdx.x * 64 + wave * 16;
    if (row0 >= num_dst) return;
    int col = lane & 15;
    int hi  = lane >> 4;
    int arow = row0 + col;
    if (arow >= num_dst) arow = num_dst - 1;
    f32x4 acc[8];
#pragma unroll
    for (int ct = 0; ct < 8; ++ct) acc[ct] = (f32x4)0.f;
    const bf16x8* A = reinterpret_cast<const bf16x8*>(aggb + (size_t)arow * DD);
#pragma unroll
    for (int kg = 0; kg < 4; ++kg) {
        bf16x8 a = A[kg * 4 + hi];
#pragma unroll
        for (int ct = 0; ct < 8; ++ct) {
            const bf16x8* B =
                reinterpret_cast<const bf16x8*>(Wt + (size_t)(ct * 16 + col) * DD);
            bf16x8 b = B[kg * 4 + hi];
            acc[ct] = __builtin_amdgcn_mfma_f32_16x16x32_bf16(a, b, acc[ct], 0, 0, 0);
        }
    }
    float wv[8], bv[8];
#pragma unroll
    for (int ct = 0; ct < 8; ++ct) {
        wv[ct] = w_attn[ct * 16 + col];
        bv[ct] = bias[ct * 16 + col];
    }
#pragma unroll
    for (int r = 0; r < 4; ++r) {
        int row = row0 + hi * 4 + r;
        float v[8];
        float s = 0.f;
#pragma unroll
        for (int ct = 0; ct < 8; ++ct) {
            v[ct] = acc[ct][r] + bv[ct];
            s = fmaf(v[ct], wv[ct], s);
        }
        s += __shfl_xor(s, 1);
        s += __shfl_xor(s, 2);
        s += __shfl_xor(s, 4);
        s += __shfl_xor(s, 8);
        float alpha = 1.0f / (1.0f + expf(-s));
        if (row < num_dst) {
#pragma unroll
            for (int ct = 0; ct < 8; ++ct)
                out[(size_t)row * DD + ct * 16 + col] = v[ct] * alpha;
            if (col == 0) alpha_out[row] = alpha;
        }
    }
}

// ----------------------------------------------------------------- launch
extern "C" void kernel_launch(void* const* d_in, const int* in_sizes, int n_in,
                              void* d_out, int out_size, void* d_ws, size_t ws_size,
                              hipStream_t stream) {
    const float* h      = (const float*)d_in[0];
    const int*   src    = (const int*)d_in[1];
    const int*   dst    = (const int*)d_in[2];
    const float* Wm     = (const float*)d_in[3];
    const float* bias   = (const float*)d_in[4];
    const float* w_attn = (const float*)d_in[5];

    int num_src = in_sizes[0] / DD;
    int E       = in_sizes[1];
    int num_dst = out_size / (DD + 1);
    int NB      = (num_dst + BKT - 1) / BKT;
    int NPASS   = (num_src + HBINS - 1) / HBINS;

    float* out       = (float*)d_out;
    float* alpha_out = out + (size_t)num_dst * DD;

    char* p = (char*)d_ws;
    auto take = [&p](size_t bytes) {
        char* q = p;
        p += (bytes + 255) & ~(size_t)255;
        return q;
    };
    unsigned int* deg_src = (unsigned int*)take((size_t)num_src * 4);
    unsigned int* cursor  = (unsigned int*)take((size_t)num_dst * 4);
    int*          csr     = (int*)take((size_t)num_dst * MAXDEG * 4);
    __hip_bfloat16* aggb  = (__hip_bfloat16*)take((size_t)num_dst * DD * 2);
    __hip_bfloat16* Wt    = (__hip_bfloat16*)take((size_t)DD * DD * 2);
    __hip_bfloat16* hb    = (__hip_bfloat16*)take((size_t)num_src * DD * 2);
    unsigned int* parts   = (unsigned int*)take(((size_t)NPASS * HBLK) << 16);
    size_t full_need = (size_t)(p - (char*)d_ws);

    // bucket-path arrays alias the (unused in that path) csr region
    unsigned int* eparts      = (unsigned int*)csr;            // E u32
    unsigned int* bucket_cnt  = eparts + ((E + 7) & ~7);       // NB
    unsigned int* bucket_base = bucket_cnt + NB + 8;           // NB+1
    unsigned int* bucket_cur  = bucket_base + NB + 8;          // NB

    bool use_mp = ws_size >= full_need;
    bool bucket_ok = use_mp && NB <= NB_MAX && num_dst <= 65536 &&
                     num_src < (1 << 24) &&
                     ((size_t)E + 3 * NB + 32) * 4 <= (size_t)num_dst * MAXDEG * 4;

    int thr = 256;
    int nHist  = NPASS * HBLK;
    int nPc    = (E + P_CH - 1) / P_CH;
    int nMerge = (num_src + 255) / 256;
    int nConv  = (num_src * (DD / 8) + 1023) / 1024;
    int nWt    = (DD * DD + 1023) / 1024;

    if (bucket_ok) {
        hipMemsetAsync(bucket_cnt, 0, (size_t)NB * 4, stream);
        k1_kernel<<<nConv + nHist + nPc + nWt, 1024, 0, stream>>>(
            h, hb, src, dst, parts, bucket_cnt, Wm, Wt, E, NB, num_src,
            nConv, nHist, nPc);
        k2_kernel<<<nMerge + 1, 256, 0, stream>>>(parts, deg_src, num_src,
                                                  bucket_cnt, bucket_base,
                                                  bucket_cur, NB, nMerge);
        k3_kernel<<<nConv + nPc, 1024, 0, stream>>>(deg_src, hb, src, dst,
                                                    bucket_cur, eparts, E, NB,
                                                    num_src, nConv);
        bgather_mfma_kernel<<<NB * 4, 256, 0, stream>>>(
            hb, eparts, bucket_base, Wt, bias, w_attn, out, alpha_out, num_dst);
    } else if (use_mp) {
        hipMemsetAsync(cursor, 0, (size_t)num_dst * 4, stream);
        k1_kernel<<<nConv + nHist + nWt, 1024, 0, stream>>>(
            h, hb, src, dst, parts, bucket_cnt, Wm, Wt, E, 0, num_src,
            nConv, nHist, 0);
        k2_kernel<<<nMerge, 256, 0, stream>>>(parts, deg_src, num_src, cursor,
                                              cursor, cursor, 0, nMerge);
        k3_kernel<<<nConv, 1024, 0, stream>>>(deg_src, hb, src, dst,
                                              cursor, (unsigned int*)csr, E, 0,
                                              num_src, nConv);
        fillc_kernel<<<(E + thr - 1) / thr, thr, 0, stream>>>(src, dst, cursor,
                                                              csr, E);
        int grid_g = (num_dst + 3) / 4;
        gather_kernel<<<grid_g, thr, 0, stream>>>(hb, csr, cursor, aggb, num_dst);
        int grid_c = (num_dst + 63) / 64;
        out_mfma_kernel<<<grid_c, thr, 0, stream>>>(aggb, Wt, bias, w_attn,
                                                    out, alpha_out, num_dst);
    } else {
        hipMemsetAsync(deg_src, 0, (size_t)num_src * 4, stream);
        hipMemsetAsync(cursor, 0, (size_t)num_dst * 4, stream);
        hist_atomic_kernel<<<(E + thr - 1) / thr, thr, 0, stream>>>(src, deg_src, E);
        k1_kernel<<<nConv + nWt, 1024, 0, stream>>>(
            h, hb, src, dst, parts, bucket_cnt, Wm, Wt, E, 0, num_src,
            nConv, 0, 0);
        k3_kernel<<<nConv, 1024, 0, stream>>>(deg_src, hb, src, dst,
                                              cursor, (unsigned int*)csr, E, 0,
                                              num_src, nConv);
        fillc_kernel<<<(E + thr - 1) / thr, thr, 0, stream>>>(src, dst, cursor,
                                                              csr, E);
        int grid_g = (num_dst + 3) / 4;
        gather_kernel<<<grid_g, thr, 0, stream>>>(hb, csr, cursor, aggb, num_dst);
        int grid_c = (num_dst + 63) / 64;
        out_mfma_kernel<<<grid_c, thr, 0, stream>>>(aggb, Wt, bias, w_attn,
                                                    out, alpha_out, num_dst);
    }
}

// Round 16
// 95.117 us; speedup vs baseline: 1.0666x; 1.0666x over previous
//
#include <hip/hip_runtime.h>
#include <hip/hip_bf16.h>
#include <math.h>

#define DD 128
#define MAXDEG 64
#define BKT 64               // dst rows per bucket (partition granularity)
#define SBKT 16              // rows per K4 block (4 blocks per bucket)
#define NB_MAX 1024
#define P_CH 8192            // edges per partition block
#define HBINS 16384          // bins per deg_src histogram pass (64KB LDS)
#define HBLK  32
#define HTHR  1024

using bf16x8 = __attribute__((ext_vector_type(8))) short;
using f32x4  = __attribute__((ext_vector_type(4))) float;

struct alignas(16) bfq { __hip_bfloat162 q[4]; };

__device__ inline float bf2f(short s) {
    unsigned int u = ((unsigned int)(unsigned short)s) << 16;
    float f;
    __builtin_memcpy(&f, &u, 4);
    return f;
}

// =============== K1: deg_src multipass hist (role A) + bucket count (role B)
__global__ __launch_bounds__(1024) void k1_kernel(
        const int* __restrict__ src, const int* __restrict__ dst,
        unsigned int* __restrict__ parts, unsigned int* __restrict__ bucket_cnt,
        int E, int NB, int nHist) {
    __shared__ unsigned int smem[HBINS];   // 64KB
    int t = threadIdx.x;
    int bid = blockIdx.x;
    if (bid < nHist) {
        int pass = bid / HBLK;
        int blk  = bid % HBLK;
        int lo   = pass * HBINS;
        for (int i = t; i < HBINS; i += 1024) smem[i] = 0;
        __syncthreads();
        int chunk = (E + HBLK - 1) / HBLK;
        int c0 = blk * chunk;
        int c1 = c0 + chunk; if (c1 > E) c1 = E;
        for (int i = c0 + t; i < c1; i += 1024) {
            unsigned int u = (unsigned int)(src[i] - lo);
            if (u < HBINS) atomicAdd(&smem[u], 1u);
        }
        __syncthreads();
        unsigned int* dstp = parts + ((size_t)bid << 14);
        for (int i = t; i < HBINS; i += 1024) dstp[i] = smem[i];
    } else {
        int b2 = bid - nHist;
        for (int b = t; b < NB; b += 1024) smem[b] = 0;
        __syncthreads();
        int c0 = b2 * P_CH;
        int c1 = c0 + P_CH; if (c1 > E) c1 = E;
        for (int i = c0 + t; i < c1; i += 1024)
            atomicAdd(&smem[dst[i] >> 6], 1u);
        __syncthreads();
        for (int b = t; b < NB; b += 1024)
            if (smem[b]) atomicAdd(&bucket_cnt[b], smem[b]);
    }
}

// =============== K2: hist merge (role A) + bucket exclusive scan (role B)
__global__ __launch_bounds__(256) void k2_kernel(
        const unsigned int* __restrict__ parts, unsigned int* __restrict__ deg_src,
        int num_src, const unsigned int* __restrict__ bucket_cnt,
        unsigned int* __restrict__ bucket_base, unsigned int* __restrict__ bucket_cur,
        int NB, int nMerge) {
    int bid = blockIdx.x;
    if (bid < nMerge) {
        int g = bid * 256 + threadIdx.x;
        if (g >= num_src) return;
        int pass = g >> 14;
        int r = g & (HBINS - 1);
        const unsigned int* p = parts + ((size_t)(pass * HBLK) << 14) + r;
        unsigned int s = 0;
#pragma unroll
        for (int b = 0; b < HBLK; ++b) s += p[(size_t)b << 14];
        deg_src[g] = s;
    } else {
        int lane = threadIdx.x;
        if (lane >= 64) return;
        unsigned int carry = 0;
        for (int b0 = 0; b0 < NB; b0 += 64) {
            int i = b0 + lane;
            unsigned int v = (i < NB) ? bucket_cnt[i] : 0u;
            unsigned int incl = v;
#pragma unroll
            for (int off = 1; off < 64; off <<= 1) {
                unsigned int u = __shfl_up(incl, off);
                if (lane >= off) incl += u;
            }
            unsigned int excl = incl - v + carry;
            if (i < NB) { bucket_base[i] = excl; bucket_cur[i] = excl; }
            carry += __shfl(incl, 63);
        }
        if (lane == 0) bucket_base[NB] = carry;
    }
}

// =============== K3: conv h->hb (role A) + W transpose (role B) + pscatter (C)
__global__ __launch_bounds__(1024) void k3_kernel(
        const float* __restrict__ h, const unsigned int* __restrict__ deg_src,
        __hip_bfloat16* __restrict__ hb, const float* __restrict__ Wm,
        __hip_bfloat16* __restrict__ Wt, const int* __restrict__ src,
        const int* __restrict__ dst, unsigned int* __restrict__ bucket_cur,
        unsigned int* __restrict__ eparts, int E, int NB, int num_src,
        int nConv, int nWt) {
    __shared__ unsigned int smem[15360];   // 60KB (pscatter role)
    int t = threadIdx.x;
    int bid = blockIdx.x;
    if (bid < nConv) {
        int idx = bid * 1024 + t;          // one thread per 8 elems
        int total = num_src * (DD / 8);
        if (idx >= total) return;
        int row = idx >> 4;
        int c0  = (idx & 15) * 8;
        float nrm = rsqrtf(fmaxf((float)deg_src[row], 1.0f));
        const float4* p = reinterpret_cast<const float4*>(h + (size_t)row * DD + c0);
        float4 a = p[0], b = p[1];
        bfq o;
        o.q[0] = __float22bfloat162_rn(make_float2(a.x * nrm, a.y * nrm));
        o.q[1] = __float22bfloat162_rn(make_float2(a.z * nrm, a.w * nrm));
        o.q[2] = __float22bfloat162_rn(make_float2(b.x * nrm, b.y * nrm));
        o.q[3] = __float22bfloat162_rn(make_float2(b.z * nrm, b.w * nrm));
        *reinterpret_cast<bfq*>(hb + (size_t)row * DD + c0) = o;
    } else if (bid < nConv + nWt) {
        int idx = (bid - nConv) * 1024 + t;
        if (idx < DD * DD) {
            int c = idx >> 7, k = idx & 127;
            Wt[idx] = __float2bfloat16(Wm[k * DD + c]);
        }
    } else {
        int b2 = bid - nConv - nWt;
        unsigned int*   stage_s = smem;                             // 8192 u32
        unsigned short* stage_d = (unsigned short*)(smem + 8192);   // 8192 u16
        unsigned int*   lhist   = smem + 12288;                     // 1024
        unsigned int*   lbase   = smem + 13312;                     // 1024
        unsigned int*   gbase   = smem + 14336;                     // 1024
        for (int b = t; b < NB_MAX; b += 1024) lhist[b] = 0;
        __syncthreads();
        int c0 = b2 * P_CH;
        int cnt = E - c0; if (cnt > P_CH) cnt = P_CH;
        int dreg[8], sreg[8];
#pragma unroll
        for (int k = 0; k < 8; ++k) {
            int j = t + k * 1024;
            if (j < cnt) {
                dreg[k] = dst[c0 + j];
                sreg[k] = src[c0 + j];
                atomicAdd(&lhist[dreg[k] >> 6], 1u);
            }
        }
        __syncthreads();
        // wave-shuffle exclusive scan of lhist[0..1023] (2 barriers)
        int wid = t >> 6, lane = t & 63;
        unsigned int v = lhist[t];
        unsigned int x = v;
#pragma unroll
        for (int off = 1; off < 64; off <<= 1) {
            unsigned int u = __shfl_up(x, off);
            if (lane >= off) x += u;
        }
        if (lane == 63) gbase[wid] = x;    // wave sums (gbase[0..15] scratch)
        __syncthreads();
        if (t < 16) {
            unsigned int w = gbase[t];
            unsigned int y = w;
#pragma unroll
            for (int off = 1; off < 16; off <<= 1) {
                unsigned int u = __shfl_up(y, off);
                if (t >= off) y += u;
            }
            gbase[t] = y - w;              // exclusive wave offset
        }
        __syncthreads();
        unsigned int excl = x - v + gbase[wid];
        __syncthreads();                    // gbase reads done before overwrite
        lbase[t] = excl;
        if (t < NB) {
            unsigned int c = lhist[t];
            gbase[t] = c ? atomicAdd(&bucket_cur[t], c) : 0u;
            lhist[t] = 0u;                 // reuse as local cursor
        }
        __syncthreads();
#pragma unroll
        for (int k = 0; k < 8; ++k) {
            int j = t + k * 1024;
            if (j < cnt) {
                int bin = dreg[k] >> 6;
                unsigned int pos = lbase[bin] + atomicAdd(&lhist[bin], 1u);
                stage_d[pos] = (unsigned short)dreg[k];
                stage_s[pos] = (unsigned int)sreg[k];
            }
        }
        __syncthreads();
        for (int idx = t; idx < cnt; idx += 1024) {
            unsigned int d = stage_d[idx];
            unsigned int bin = d >> 6;
            unsigned int pos = gbase[bin] + ((unsigned int)idx - lbase[bin]);
            eparts[pos] = ((d & 63u) << 24) | stage_s[idx];
        }
    }
}

// =============== K4: sub-bucket gather + MFMA GEMM + attention epilogue
// 4 blocks per bucket; block = 256 thr = 4 waves; 16 rows; 8-edge unroll
__global__ __launch_bounds__(256) void bgather_mfma_kernel(
        const __hip_bfloat16* __restrict__ hb,
        const unsigned int* __restrict__ eparts,
        const unsigned int* __restrict__ bucket_base,
        const __hip_bfloat16* __restrict__ Wt,
        const float* __restrict__ bias, const float* __restrict__ w_attn,
        float* __restrict__ out, float* __restrict__ alpha_out, int num_dst) {
    __shared__ unsigned int lcsr[SBKT * MAXDEG];   // 4KB
    __shared__ unsigned int cur[SBKT];
    __shared__ __hip_bfloat16 sagg[SBKT * DD];     // 4KB, XOR-swizzled
    int t = threadIdx.x, wid = t >> 6, lane = t & 63;
    int b = blockIdx.x >> 2;
    unsigned int quarter = blockIdx.x & 3;
    if (t < SBKT) cur[t] = 0;
    __syncthreads();
    unsigned int e0 = bucket_base[b], e1 = bucket_base[b + 1];
    for (unsigned int i = e0 + t; i < e1; i += 256) {
        unsigned int e = eparts[i];
        unsigned int dlow = e >> 24;
        if ((dlow >> 4) == quarter) {
            unsigned int pos = atomicAdd(&cur[dlow & 15], 1u);   // LDS int atomic
            if (pos < MAXDEG) lcsr[(dlow & 15) * MAXDEG + pos] = e & 0xFFFFFFu;
        }
    }
    __syncthreads();

    const bf16x8* hb8 = reinterpret_cast<const bf16x8*>(hb);  // 16 chunks/row
    char* sb = (char*)sagg;
    int g  = lane >> 4;     // row-group 0..3
    int gl = lane & 15;     // 16B chunk within row
    {
        int r = wid * 4 + g;                 // 0..15
        unsigned int degu = cur[r];
        int deg = (int)degu; if (deg > MAXDEG) deg = MAXDEG;
        const unsigned int* crow = &lcsr[r * MAXDEG];
        float acc[8];
#pragma unroll
        for (int j = 0; j < 8; ++j) acc[j] = 0.f;
        int i = 0;
        for (; i + 8 <= deg; i += 8) {
            uint4 qa = *reinterpret_cast<const uint4*>(crow + i);      // broadcast
            uint4 qb = *reinterpret_cast<const uint4*>(crow + i + 4);
            bf16x8 v0 = hb8[(size_t)qa.x * 16 + gl];
            bf16x8 v1 = hb8[(size_t)qa.y * 16 + gl];
            bf16x8 v2 = hb8[(size_t)qa.z * 16 + gl];
            bf16x8 v3 = hb8[(size_t)qa.w * 16 + gl];
            bf16x8 v4 = hb8[(size_t)qb.x * 16 + gl];
            bf16x8 v5 = hb8[(size_t)qb.y * 16 + gl];
            bf16x8 v6 = hb8[(size_t)qb.z * 16 + gl];
            bf16x8 v7 = hb8[(size_t)qb.w * 16 + gl];
#pragma unroll
            for (int j = 0; j < 8; ++j)
                acc[j] += ((bf2f(v0[j]) + bf2f(v1[j])) + (bf2f(v2[j]) + bf2f(v3[j])))
                        + ((bf2f(v4[j]) + bf2f(v5[j])) + (bf2f(v6[j]) + bf2f(v7[j])));
        }
        for (; i + 4 <= deg; i += 4) {
            uint4 q = *reinterpret_cast<const uint4*>(crow + i);
            bf16x8 v0 = hb8[(size_t)q.x * 16 + gl];
            bf16x8 v1 = hb8[(size_t)q.y * 16 + gl];
            bf16x8 v2 = hb8[(size_t)q.z * 16 + gl];
            bf16x8 v3 = hb8[(size_t)q.w * 16 + gl];
#pragma unroll
            for (int j = 0; j < 8; ++j)
                acc[j] += (bf2f(v0[j]) + bf2f(v1[j])) + (bf2f(v2[j]) + bf2f(v3[j]));
        }
        for (; i < deg; ++i) {
            bf16x8 v = hb8[(size_t)crow[i] * 16 + gl];
#pragma unroll
            for (int j = 0; j < 8; ++j) acc[j] += bf2f(v[j]);
        }
        float scd = rsqrtf(fmaxf((float)degu, 1.0f));
        bfq o;
#pragma unroll
        for (int j = 0; j < 4; ++j)
            o.q[j] = __float22bfloat162_rn(
                make_float2(acc[2 * j] * scd, acc[2 * j + 1] * scd));
        int byte = r * 256 + gl * 16;
        *reinterpret_cast<bfq*>(sb + (byte ^ ((r & 7) << 4))) = o;
    }
    __syncthreads();

    if (wid == 0) {
        int col = lane & 15, hi = lane >> 4;
        int row0 = b * 64 + quarter * 16;
        f32x4 acc[8];
#pragma unroll
        for (int ct = 0; ct < 8; ++ct) acc[ct] = (f32x4)0.f;
#pragma unroll
        for (int kg = 0; kg < 4; ++kg) {
            int byte = col * 256 + (kg * 32 + hi * 8) * 2;
            bf16x8 a = *reinterpret_cast<const bf16x8*>(
                sb + (byte ^ ((col & 7) << 4)));
#pragma unroll
            for (int ct = 0; ct < 8; ++ct) {
                const bf16x8* B = reinterpret_cast<const bf16x8*>(
                    Wt + (size_t)(ct * 16 + col) * DD);
                bf16x8 bb = B[kg * 4 + hi];
                acc[ct] = __builtin_amdgcn_mfma_f32_16x16x32_bf16(a, bb, acc[ct],
                                                                  0, 0, 0);
            }
        }
        float wv[8], bv[8];
#pragma unroll
        for (int ct = 0; ct < 8; ++ct) {
            wv[ct] = w_attn[ct * 16 + col];
            bv[ct] = bias[ct * 16 + col];
        }
#pragma unroll
        for (int r = 0; r < 4; ++r) {
            int row = row0 + hi * 4 + r;
            float v[8];
            float s = 0.f;
#pragma unroll
            for (int ct = 0; ct < 8; ++ct) {
                v[ct] = acc[ct][r] + bv[ct];
                s = fmaf(v[ct], wv[ct], s);
            }
            s += __shfl_xor(s, 1);
            s += __shfl_xor(s, 2);
            s += __shfl_xor(s, 4);
            s += __shfl_xor(s, 8);
            float alpha = 1.0f / (1.0f + expf(-s));
            if (row < num_dst) {
#pragma unroll
                for (int ct = 0; ct < 8; ++ct)
                    out[(size_t)row * DD + ct * 16 + col] = v[ct] * alpha;
                if (col == 0) alpha_out[row] = alpha;
            }
        }
    }
}

// =============== fallback-path kernels (non-bucket shapes / small ws)
__global__ void hist_atomic_kernel(const int* __restrict__ src,
                                   unsigned int* __restrict__ deg_src, int E) {
    int i = blockIdx.x * blockDim.x + threadIdx.x;
    if (i < E) atomicAdd(&deg_src[src[i]], 1u);
}

__global__ void fillc_kernel(const int* __restrict__ src, const int* __restrict__ dst,
                             unsigned int* __restrict__ cursor,
                             int* __restrict__ csr, int E) {
    int i = blockIdx.x * blockDim.x + threadIdx.x;
    if (i < E) {
        int s = src[i];
        int d = dst[i];
        unsigned int pos = atomicAdd(&cursor[d], 1u);
        if (pos < MAXDEG) csr[(size_t)d * MAXDEG + pos] = s;
    }
}

__global__ __launch_bounds__(256) void gather_kernel(
        const __hip_bfloat16* __restrict__ hb,
        const int* __restrict__ csr, const unsigned int* __restrict__ cursor,
        __hip_bfloat16* __restrict__ aggb, int num_dst) {
    int wave = threadIdx.x >> 6;
    int lane = threadIdx.x & 63;
    int row = blockIdx.x * 4 + wave;
    if (row >= num_dst) return;
    unsigned int degu = cursor[row];
    int deg = (int)degu; if (deg > MAXDEG) deg = MAXDEG;
    const int* crow = csr + (size_t)row * MAXDEG;
    int c = lane * 2;
    float ax = 0.f, ay = 0.f;
    int i = 0;
    for (; i + 4 <= deg; i += 4) {
        int4 s0 = *reinterpret_cast<const int4*>(crow + i);
        float2 v0 = __bfloat1622float2(*reinterpret_cast<const __hip_bfloat162*>(hb + (size_t)s0.x * DD + c));
        float2 v1 = __bfloat1622float2(*reinterpret_cast<const __hip_bfloat162*>(hb + (size_t)s0.y * DD + c));
        float2 v2 = __bfloat1622float2(*reinterpret_cast<const __hip_bfloat162*>(hb + (size_t)s0.z * DD + c));
        float2 v3 = __bfloat1622float2(*reinterpret_cast<const __hip_bfloat162*>(hb + (size_t)s0.w * DD + c));
        ax += v0.x + v1.x + v2.x + v3.x;
        ay += v0.y + v1.y + v2.y + v3.y;
    }
    for (; i < deg; ++i) {
        int s = crow[i];
        float2 vv = __bfloat1622float2(*reinterpret_cast<const __hip_bfloat162*>(hb + (size_t)s * DD + c));
        ax += vv.x; ay += vv.y;
    }
    float scd = rsqrtf(fmaxf((float)degu, 1.0f));
    *reinterpret_cast<__hip_bfloat162*>(aggb + (size_t)row * DD + c) =
        __float22bfloat162_rn(make_float2(ax * scd, ay * scd));
}

__global__ __launch_bounds__(256) void out_mfma_kernel(
        const __hip_bfloat16* __restrict__ aggb,
        const __hip_bfloat16* __restrict__ Wt,
        const float* __restrict__ bias, const float* __restrict__ w_attn,
        float* __restrict__ out, float* __restrict__ alpha_out, int num_dst) {
    int wave = threadIdx.x >> 6;
    int lane = threadIdx.x & 63;
    int row0 = blockIdx.x * 64 + wave * 16;
    if (row0 >= num_dst) return;
    int col = lane & 15;
    int hi  = lane >> 4;
    int arow = row0 + col;
    if (arow >= num_dst) arow = num_dst - 1;
    f32x4 acc[8];
#pragma unroll
    for (int ct = 0; ct < 8; ++ct) acc[ct] = (f32x4)0.f;
    const bf16x8* A = reinterpret_cast<const bf16x8*>(aggb + (size_t)arow * DD);
#pragma unroll
    for (int kg = 0; kg < 4; ++kg) {
        bf16x8 a = A[kg * 4 + hi];
#pragma unroll
        for (int ct = 0; ct < 8; ++ct) {
            const bf16x8* B =
                reinterpret_cast<const bf16x8*>(Wt + (size_t)(ct * 16 + col) * DD);
            bf16x8 b = B[kg * 4 + hi];
            acc[ct] = __builtin_amdgcn_mfma_f32_16x16x32_bf16(a, b, acc[ct], 0, 0, 0);
        }
    }
    float wv[8], bv[8];
#pragma unroll
    for (int ct = 0; ct < 8; ++ct) {
        wv[ct] = w_attn[ct * 16 + col];
        bv[ct] = bias[ct * 16 + col];
    }
#pragma unroll
    for (int r = 0; r < 4; ++r) {
        int row = row0 + hi * 4 + r;
        float v[8];
        float s = 0.f;
#pragma unroll
        for (int ct = 0; ct < 8; ++ct) {
            v[ct] = acc[ct][r] + bv[ct];
            s = fmaf(v[ct], wv[ct], s);
        }
        s += __shfl_xor(s, 1);
        s += __shfl_xor(s, 2);
        s += __shfl_xor(s, 4);
        s += __shfl_xor(s, 8);
        float alpha = 1.0f / (1.0f + expf(-s));
        if (row < num_dst) {
#pragma unroll
            for (int ct = 0; ct < 8; ++ct)
                out[(size_t)row * DD + ct * 16 + col] = v[ct] * alpha;
            if (col == 0) alpha_out[row] = alpha;
        }
    }
}

// ----------------------------------------------------------------- launch
extern "C" void kernel_launch(void* const* d_in, const int* in_sizes, int n_in,
                              void* d_out, int out_size, void* d_ws, size_t ws_size,
                              hipStream_t stream) {
    const float* h      = (const float*)d_in[0];
    const int*   src    = (const int*)d_in[1];
    const int*   dst    = (const int*)d_in[2];
    const float* Wm     = (const float*)d_in[3];
    const float* bias   = (const float*)d_in[4];
    const float* w_attn = (const float*)d_in[5];

    int num_src = in_sizes[0] / DD;
    int E       = in_sizes[1];
    int num_dst = out_size / (DD + 1);
    int NB      = (num_dst + BKT - 1) / BKT;
    int NPASS   = (num_src + HBINS - 1) / HBINS;

    float* out       = (float*)d_out;
    float* alpha_out = out + (size_t)num_dst * DD;

    char* p = (char*)d_ws;
    auto take = [&p](size_t bytes) {
        char* q = p;
        p += (bytes + 255) & ~(size_t)255;
        return q;
    };
    unsigned int* deg_src = (unsigned int*)take((size_t)num_src * 4);
    unsigned int* cursor  = (unsigned int*)take((size_t)num_dst * 4);
    int*          csr     = (int*)take((size_t)num_dst * MAXDEG * 4);
    __hip_bfloat16* aggb  = (__hip_bfloat16*)take((size_t)num_dst * DD * 2);
    __hip_bfloat16* Wt    = (__hip_bfloat16*)take((size_t)DD * DD * 2);
    __hip_bfloat16* hb    = (__hip_bfloat16*)take((size_t)num_src * DD * 2);
    unsigned int* parts   = (unsigned int*)take(((size_t)NPASS * HBLK) << 16);
    size_t full_need = (size_t)(p - (char*)d_ws);

    // bucket-path arrays alias the (unused in that path) csr region
    unsigned int* eparts      = (unsigned int*)csr;            // E u32
    unsigned int* bucket_cnt  = eparts + ((E + 7) & ~7);       // NB
    unsigned int* bucket_base = bucket_cnt + NB + 8;           // NB+1
    unsigned int* bucket_cur  = bucket_base + NB + 8;          // NB

    bool use_mp = ws_size >= full_need;
    bool bucket_ok = use_mp && NB <= NB_MAX && num_dst <= 65536 &&
                     num_src < (1 << 24) &&
                     ((size_t)E + 3 * NB + 32) * 4 <= (size_t)num_dst * MAXDEG * 4;

    int thr = 256;
    int nHist  = NPASS * HBLK;
    int nPc    = (E + P_CH - 1) / P_CH;
    int nMerge = (num_src + 255) / 256;
    int nConv  = (num_src * (DD / 8) + 1023) / 1024;
    int nWt    = (DD * DD + 1023) / 1024;

    if (bucket_ok) {
        hipMemsetAsync(bucket_cnt, 0, (size_t)NB * 4, stream);
        k1_kernel<<<nHist + nPc, 1024, 0, stream>>>(src, dst, parts, bucket_cnt,
                                                    E, NB, nHist);
        k2_kernel<<<nMerge + 1, 256, 0, stream>>>(parts, deg_src, num_src,
                                                  bucket_cnt, bucket_base,
                                                  bucket_cur, NB, nMerge);
        k3_kernel<<<nConv + nWt + nPc, 1024, 0, stream>>>(
            h, deg_src, hb, Wm, Wt, src, dst, bucket_cur, eparts, E, NB, num_src,
            nConv, nWt);
        bgather_mfma_kernel<<<NB * 4, 256, 0, stream>>>(hb, eparts, bucket_base, Wt,
                                                        bias, w_attn, out, alpha_out,
                                                        num_dst);
    } else if (use_mp) {
        hipMemsetAsync(cursor, 0, (size_t)num_dst * 4, stream);
        k1_kernel<<<nHist, 1024, 0, stream>>>(src, dst, parts, cursor /*unused*/,
                                              E, 0, nHist);
        k2_kernel<<<nMerge, 256, 0, stream>>>(parts, deg_src, num_src, cursor,
                                              cursor, cursor, 0, nMerge);
        fillc_kernel<<<(E + thr - 1) / thr, thr, 0, stream>>>(src, dst, cursor,
                                                              csr, E);
        k3_kernel<<<nConv + nWt, 1024, 0, stream>>>(
            h, deg_src, hb, Wm, Wt, src, dst, cursor, (unsigned int*)csr, E, 0,
            num_src, nConv, nWt);
        int grid_g = (num_dst + 3) / 4;
        gather_kernel<<<grid_g, thr, 0, stream>>>(hb, csr, cursor, aggb, num_dst);
        int grid_c = (num_dst + 63) / 64;
        out_mfma_kernel<<<grid_c, thr, 0, stream>>>(aggb, Wt, bias, w_attn,
                                                    out, alpha_out, num_dst);
    } else {
        hipMemsetAsync(deg_src, 0, (size_t)num_src * 4, stream);
        hipMemsetAsync(cursor, 0, (size_t)num_dst * 4, stream);
        hist_atomic_kernel<<<(E + thr - 1) / thr, thr, 0, stream>>>(src, deg_src, E);
        fillc_kernel<<<(E + thr - 1) / thr, thr, 0, stream>>>(src, dst, cursor,
                                                              csr, E);
        k3_kernel<<<nConv + nWt, 1024, 0, stream>>>(
            h, deg_src, hb, Wm, Wt, src, dst, cursor, (unsigned int*)csr, E, 0,
            num_src, nConv, nWt);
        int grid_g = (num_dst + 3) / 4;
        gather_kernel<<<grid_g, thr, 0, stream>>>(hb, csr, cursor, aggb, num_dst);
        int grid_c = (num_dst + 63) / 64;
        out_mfma_kernel<<<grid_c, thr, 0, stream>>>(aggb, Wt, bias, w_attn,
                                                    out, alpha_out, num_dst);
    }
}